// Round 4
// baseline (947.083 us; speedup 1.0000x reference)
//
#include <hip/hip_runtime.h>
#include <math.h>

#define NN 80000
#define NE 2560000
#define NBK 313            // ceil(NN/256) buckets of 256 cols
#define BN_EPS 1e-5f

typedef __attribute__((ext_vector_type(8))) short short8;
typedef __attribute__((ext_vector_type(4))) float f32x4;

// ---------------- workspace layout (f32 index units, all 16B-aligned) ----------------
#define OFF_DIS     0                       // NN f32
#define OFF_ROWPTR  80000                   // NN+2 ints
#define OFF_CURSOR  160004                  // NN ints (only first NBK used: bcursor)
#define OFF_DEG     240004                  // NN ints
#define OFF_PERM    320004                  // 2*NE ints (int2)
#define OFF_XB      (OFF_PERM + 2*NE)       // N*128 bf16 = N*64 f32
#define OFF_RDB     (OFF_XB + NN*64)        // N*32 bf16
#define OFF_B1      (OFF_RDB + NN*16)       // N*64 bf16 (or N*32 f32)
#define OFF_B2      (OFF_B1 + NN*32)
#define OFF_B3      (OFF_B2 + NN*32)
#define OFF_WP      (OFF_B3 + NN*32)        // 40960 ushorts = 20480 f32
#define OFF_BV      (OFF_WP + 20480)        // 5*64 f32
#define OFF_STATS   (OFF_BV + 320)          // 1920 f32
// pbuf (2*NE ints) aliases B1+B2: used only before first k_mfma.
// stats: 0 xsum[128] /128 xsq[128] /256 h0s /320 h0q /384 h1s /448 h1q
//        /512 m0s /576 m0q /640 m1s /704 m1q /768 m2s[32] /800 m2q[32]
//        /1856 sm2[32] /1888 sh2[32]

__device__ __forceinline__ ushort f2b(float f) {
    union { float f; unsigned u; } x; x.f = f;
    return (ushort)((x.u + 0x7FFF + ((x.u >> 16) & 1)) >> 16);
}
__device__ __forceinline__ float b2f(ushort u) {
    union { unsigned u; float f; } x; x.u = ((unsigned)u) << 16;
    return x.f;
}

__global__ void k_deg(const int* __restrict__ col, int* __restrict__ deg) {
    int e = blockIdx.x * blockDim.x + threadIdx.x;
    if (e < NE) atomicAdd(&deg[col[e]], 1);
}

// scan deg -> rowptr; also dis = deg>0 ? rsqrt(deg) : 0
__global__ void __launch_bounds__(1024) k_scan(const int* __restrict__ deg,
                                               int* __restrict__ rowptr,
                                               float* __restrict__ dis) {
    __shared__ int ssum[1024];
    int t = threadIdx.x;
    const int CH = (NN + 1023) / 1024;
    int beg = t * CH, end = beg + CH < NN ? beg + CH : NN;
    int s = 0;
    for (int i = beg; i < end; i++) {
        int d = deg[i];
        dis[i] = d > 0 ? rsqrtf((float)d) : 0.f;
        s += d;
    }
    ssum[t] = s;
    __syncthreads();
    for (int off = 1; off < 1024; off <<= 1) {
        int v = (t >= off) ? ssum[t - off] : 0;
        __syncthreads();
        ssum[t] += v;
        __syncthreads();
    }
    int pre = (t == 0) ? 0 : ssum[t - 1];
    for (int i = beg; i < end; i++) { rowptr[i] = pre; pre += deg[i]; }
    if (t == 1023) rowptr[NN] = ssum[1023];
}

// pass 1: bucket-scatter edge records. record = (row<<8 | col&255, coef bits)
// pbase[b] = rowptr[b<<8]; per-block ranks via LDS hist, block claims global range.
__global__ void __launch_bounds__(256) k_scat1(const int* __restrict__ erow,
                                               const int* __restrict__ ecol,
                                               const float* __restrict__ mask,
                                               const float* __restrict__ dis,
                                               const int* __restrict__ rowptr,
                                               int* __restrict__ bcursor,
                                               int2* __restrict__ pbuf) {
    __shared__ int hist[NBK], base[NBK];
    for (int i = threadIdx.x; i < NBK; i += 256) hist[i] = 0;
    __syncthreads();
    int e0 = blockIdx.x * 4096;
    int r[16], c[16], rk[16];
    float cf[16];
    #pragma unroll
    for (int i = 0; i < 16; i++) {
        int e = e0 + i * 256 + threadIdx.x;
        if (e < NE) {
            r[i] = erow[e]; c[i] = ecol[e];
            cf[i] = dis[r[i]] * dis[c[i]] * mask[e];
            rk[i] = atomicAdd(&hist[c[i] >> 8], 1);
        } else c[i] = -1;
    }
    __syncthreads();
    for (int b = threadIdx.x; b < NBK; b += 256) {
        int h = hist[b];
        base[b] = h ? atomicAdd(&bcursor[b], h) : 0;
    }
    __syncthreads();
    #pragma unroll
    for (int i = 0; i < 16; i++) {
        if (c[i] >= 0) {
            int b = c[i] >> 8;
            int addr = rowptr[b << 8] + base[b] + rk[i];
            pbuf[addr] = make_int2((r[i] << 8) | (c[i] & 255), __float_as_int(cf[i]));
        }
    }
}

// pass 2: per-bucket finalize into exact CSR slots (all traffic within ~65KB window)
__global__ void __launch_bounds__(256) k_scat2(const int* __restrict__ rowptr,
                                               const int2* __restrict__ pbuf,
                                               int2* __restrict__ perm) {
    __shared__ int rbase[257];
    __shared__ int lcur[256];
    int b = blockIdx.x;
    int c0 = b << 8;
    int ncols = (NN - c0) < 256 ? (NN - c0) : 256;
    int s0 = rowptr[c0];
    if (threadIdx.x < ncols) rbase[threadIdx.x] = rowptr[c0 + threadIdx.x] - s0;
    if (threadIdx.x == 0) rbase[ncols] = rowptr[c0 + ncols] - s0;
    lcur[threadIdx.x] = 0;
    __syncthreads();
    int cnt = rbase[ncols];
    for (int i = threadIdx.x; i < cnt; i += 256) {
        int2 rec = pbuf[s0 + i];
        int crel = rec.x & 255;
        int rr = rec.x >> 8;
        int slot = rbase[crel] + atomicAdd(&lcur[crel], 1);
        perm[s0 + slot] = make_int2(rr, rec.y);
    }
}

// build xb [N,128] bf16, rdb [N,32] bf16 (cols 16-31 zero); fused x1/x2 column stats
__global__ void __launch_bounds__(256) k_prepstats(const float* __restrict__ x1,
                                                   const float* __restrict__ x2,
                                                   const float* __restrict__ rd,
                                                   ushort* __restrict__ xb,
                                                   ushort* __restrict__ rdb,
                                                   float* __restrict__ st) {
    int wave = threadIdx.x >> 6, lane = threadIdx.x & 63;
    float s1 = 0, q1 = 0, s2 = 0, q2 = 0;
    for (int n = blockIdx.x * 4 + wave; n < NN; n += gridDim.x * 4) {
        float a = x1[(size_t)n * 64 + lane];
        float b = x2[(size_t)n * 64 + lane];
        s1 += a; q1 += a * a; s2 += b; q2 += b * b;
        xb[(size_t)n * 128 + lane]      = f2b(a);
        xb[(size_t)n * 128 + 64 + lane] = f2b(b);
        if (lane < 32)
            rdb[(size_t)n * 32 + lane] = lane < 16 ? f2b(rd[(size_t)n * 16 + lane]) : 0;
    }
    __shared__ float red[4][256];
    red[0][threadIdx.x] = s1; red[1][threadIdx.x] = q1;
    red[2][threadIdx.x] = s2; red[3][threadIdx.x] = q2;
    __syncthreads();
    if (threadIdx.x < 64) {
        int l = threadIdx.x;
        atomicAdd(&st[l],       red[0][l] + red[0][l+64] + red[0][l+128] + red[0][l+192]);
        atomicAdd(&st[128 + l], red[1][l] + red[1][l+64] + red[1][l+128] + red[1][l+192]);
        atomicAdd(&st[64 + l],  red[2][l] + red[2][l+64] + red[2][l+128] + red[2][l+192]);
        atomicAdd(&st[192 + l], red[3][l] + red[3][l+64] + red[3][l+128] + red[3][l+192]);
    }
}

// pack lin0 weights (144x64 f32, zero-padded to 160 rows) into MFMA B-frag order
__global__ void k_foldw0(const float* __restrict__ W, ushort* __restrict__ Wp) {
    for (int idx = threadIdx.x; idx < 160 * 64; idx += 256) {
        int k = idx >> 6, c = idx & 63;
        float val = k < 144 ? W[k * 64 + c] : 0.f;
        int ks = k >> 5, j = k & 7, kg = (k >> 3) & 3;
        int l = kg * 16 + (c & 15), ct = c >> 4;
        Wp[((ks * 4 + ct) * 64 + l) * 8 + j] = f2b(val);
    }
}

// BN(192) finalize + fold into packed weights and bias vector
__global__ void k_bnfold192(const float* __restrict__ xs,
                            const float* __restrict__ hsum, const float* __restrict__ hsq,
                            const float* __restrict__ g, const float* __restrict__ bnb,
                            const float* __restrict__ W,     // 192x64 f32
                            const float* __restrict__ bias,  // or null
                            ushort* __restrict__ Wp, float* __restrict__ bvec) {
    __shared__ float scale[192], shift[192];
    int t = threadIdx.x;
    if (t < 192) {
        float s = t < 128 ? xs[t] : hsum[t - 128];
        float q = t < 128 ? xs[128 + t] : hsq[t - 128];
        float m = s * (1.f / NN);
        float var = q * (1.f / NN) - m * m;
        float sc = g[t] * rsqrtf(var + BN_EPS);
        scale[t] = sc;
        shift[t] = bnb[t] - m * sc;
    }
    __syncthreads();
    for (int idx = t; idx < 192 * 64; idx += 256) {
        int k = idx >> 6, c = idx & 63;
        float val = scale[k] * W[idx];
        int ks = k >> 5, j = k & 7, kg = (k >> 3) & 3;
        int l = kg * 16 + (c & 15), ct = c >> 4;
        Wp[((ks * 4 + ct) * 64 + l) * 8 + j] = f2b(val);
    }
    if (t < 64) {
        float acc = bias ? bias[t] : 0.f;
        for (int k = 0; k < 192; k++) acc += shift[k] * W[k * 64 + t];
        bvec[t] = acc;
    }
}

// BN(64) finalize + fold (NCw = 64 or 32 output cols)
__global__ void k_bnfold64(const float* __restrict__ sum, const float* __restrict__ sq,
                           const float* __restrict__ g, const float* __restrict__ bnb,
                           const float* __restrict__ W, const float* __restrict__ bias,
                           ushort* __restrict__ Wp, float* __restrict__ bvec, int NCw) {
    __shared__ float scale[64], shift[64];
    int t = threadIdx.x;
    if (t < 64) {
        float m = sum[t] * (1.f / NN);
        float var = sq[t] * (1.f / NN) - m * m;
        float sc = g[t] * rsqrtf(var + BN_EPS);
        scale[t] = sc;
        shift[t] = bnb[t] - m * sc;
    }
    __syncthreads();
    int NCOLT = NCw >> 4;
    for (int idx = t; idx < 64 * NCw; idx += 256) {
        int k = idx / NCw, c = idx % NCw;
        float val = scale[k] * W[idx];
        int ks = k >> 5, j = k & 7, kg = (k >> 3) & 3;
        int l = kg * 16 + (c & 15), ct = c >> 4;
        Wp[((ks * NCOLT + ct) * 64 + l) * 8 + j] = f2b(val);
    }
    if (t < NCw) {
        float acc = bias[t];
        for (int k = 0; k < 64; k++) acc += shift[k] * W[k * NCw + t];
        bvec[t] = acc;
    }
}

__global__ void k_bnfin(const float* __restrict__ sum, const float* __restrict__ sq,
                        const float* __restrict__ g, const float* __restrict__ b,
                        float* __restrict__ scale, float* __restrict__ shift) {
    int c = threadIdx.x;
    float m = sum[c] * (1.f / NN);
    float var = sq[c] * (1.f / NN) - m * m;
    float sc = g[c] * rsqrtf(var + BN_EPS);
    scale[c] = sc;
    shift[c] = b[c] - m * sc;
}

// ---------------- MFMA GEMM: out[N, NC] = A[N, K] @ Wp + bvec ----------------
template <int KSTEPS, int NCOLT, int KS1, int S1, int S2, bool EPI, bool OUTF32>
__global__ void __launch_bounds__(256) k_mfma(const ushort* __restrict__ A1,
                                              const ushort* __restrict__ A2,
                                              const ushort* __restrict__ Wp,
                                              const float* __restrict__ bvec,
                                              void* __restrict__ out,
                                              float* __restrict__ sum,
                                              float* __restrict__ sq) {
    const int NC = NCOLT * 16;
    __shared__ float cs[NC], cq[NC];
    int wave = threadIdx.x >> 6, lane = threadIdx.x & 63;
    int r0 = lane & 15, kg = lane >> 4;
    int rbase = blockIdx.x * 64 + wave * 16;
    if (EPI) {
        if (threadIdx.x < NC) { cs[threadIdx.x] = 0.f; cq[threadIdx.x] = 0.f; }
        __syncthreads();
    }
    f32x4 acc[NCOLT];
    #pragma unroll
    for (int ct = 0; ct < NCOLT; ct++) acc[ct] = (f32x4){0.f, 0.f, 0.f, 0.f};
    #pragma unroll
    for (int ks = 0; ks < KSTEPS; ks++) {
        const ushort* src = (ks < KS1)
            ? A1 + (size_t)(rbase + r0) * S1 + ks * 32 + kg * 8
            : A2 + (size_t)(rbase + r0) * S2 + (ks - KS1) * 32 + kg * 8;
        short8 a = *reinterpret_cast<const short8*>(src);
        #pragma unroll
        for (int ct = 0; ct < NCOLT; ct++) {
            short8 b = *reinterpret_cast<const short8*>(Wp + ((size_t)(ks * NCOLT + ct) * 64 + lane) * 8);
            acc[ct] = __builtin_amdgcn_mfma_f32_16x16x32_bf16(a, b, acc[ct], 0, 0, 0);
        }
    }
    float ss[NCOLT], qq[NCOLT];
    #pragma unroll
    for (int ct = 0; ct < NCOLT; ct++) {
        int c = ct * 16 + r0;
        float bv = bvec[c];
        ss[ct] = 0.f; qq[ct] = 0.f;
        #pragma unroll
        for (int r = 0; r < 4; r++) {
            int row = rbase + kg * 4 + r;
            float v = acc[ct][r] + bv;
            if (EPI) {
                v = v > 0.f ? v : (__expf(v) - 1.f);
                ss[ct] += v; qq[ct] += v * v;
            }
            if (OUTF32) ((float*)out)[(size_t)row * NC + c] = v;
            else        ((ushort*)out)[(size_t)row * NC + c] = f2b(v);
        }
    }
    if (EPI) {
        #pragma unroll
        for (int ct = 0; ct < NCOLT; ct++) {
            int c = ct * 16 + r0;
            atomicAdd(&cs[c], ss[ct]);
            atomicAdd(&cq[c], qq[ct]);
        }
        __syncthreads();
        if (threadIdx.x < NC) {
            atomicAdd(&sum[threadIdx.x], cs[threadIdx.x]);
            atomicAdd(&sq[threadIdx.x], cq[threadIdx.x]);
        }
    }
}

// CSR gather-aggregate, 8-deep unrolled, dual accumulators
__global__ void __launch_bounds__(256) k_gather(const int* __restrict__ rowptr,
                                                const int2* __restrict__ perm,
                                                const ushort* __restrict__ h,
                                                const float* __restrict__ bias,
                                                ushort* __restrict__ out,
                                                float* __restrict__ sum,
                                                float* __restrict__ sq) {
    int wave = threadIdx.x >> 6, lane = threadIdx.x & 63;
    float bs = bias[lane];
    float s = 0, q = 0;
    for (int n = blockIdx.x * 4 + wave; n < NN; n += gridDim.x * 4) {
        int beg = rowptr[n], end = rowptr[n + 1];
        float acc0 = 0.f, acc1 = 0.f;
        int e = beg;
        for (; e + 8 <= end; e += 8) {
            int2 p0 = perm[e],     p1 = perm[e + 1], p2 = perm[e + 2], p3 = perm[e + 3];
            int2 p4 = perm[e + 4], p5 = perm[e + 5], p6 = perm[e + 6], p7 = perm[e + 7];
            float v0 = b2f(h[(size_t)p0.x * 64 + lane]);
            float v1 = b2f(h[(size_t)p1.x * 64 + lane]);
            float v2 = b2f(h[(size_t)p2.x * 64 + lane]);
            float v3 = b2f(h[(size_t)p3.x * 64 + lane]);
            float v4 = b2f(h[(size_t)p4.x * 64 + lane]);
            float v5 = b2f(h[(size_t)p5.x * 64 + lane]);
            float v6 = b2f(h[(size_t)p6.x * 64 + lane]);
            float v7 = b2f(h[(size_t)p7.x * 64 + lane]);
            acc0 += __int_as_float(p0.y) * v0; acc1 += __int_as_float(p1.y) * v1;
            acc0 += __int_as_float(p2.y) * v2; acc1 += __int_as_float(p3.y) * v3;
            acc0 += __int_as_float(p4.y) * v4; acc1 += __int_as_float(p5.y) * v5;
            acc0 += __int_as_float(p6.y) * v6; acc1 += __int_as_float(p7.y) * v7;
        }
        for (; e < end; e++) {
            int2 p = perm[e];
            acc0 += __int_as_float(p.y) * b2f(h[(size_t)p.x * 64 + lane]);
        }
        float v = acc0 + acc1 + bs;
        v = v > 0.f ? v : (__expf(v) - 1.f);
        out[(size_t)n * 64 + lane] = f2b(v);
        s += v; q += v * v;
    }
    __shared__ float rs[256], rq[256];
    rs[threadIdx.x] = s; rq[threadIdx.x] = q;
    __syncthreads();
    if (threadIdx.x < 64) {
        int l = threadIdx.x;
        atomicAdd(&sum[l], rs[l] + rs[l + 64] + rs[l + 128] + rs[l + 192]);
        atomicAdd(&sq[l],  rq[l] + rq[l + 64] + rq[l + 128] + rq[l + 192]);
    }
}

__global__ void k_out(const float* __restrict__ u2, const float* __restrict__ scale,
                      const float* __restrict__ shift, float* __restrict__ out) {
    int t = blockIdx.x * blockDim.x + threadIdx.x;
    if (t < NN * 32) {
        int c = t & 31;
        out[t] = u2[t] * scale[c] + shift[c];
    }
}

extern "C" void kernel_launch(void* const* d_in, const int* in_sizes, int n_in,
                              void* d_out, int out_size, void* d_ws, size_t ws_size,
                              hipStream_t stream) {
    const float* x1 = (const float*)d_in[0];
    const float* x2 = (const float*)d_in[1];
    const float* rd = (const float*)d_in[2];
    const float* mask = (const float*)d_in[4];
    const int* ei = (const int*)d_in[5];
    const int* erow = ei;
    const int* ecol = ei + NE;
    const float* conv0_w = (const float*)d_in[6];
    const float* conv0_b = (const float*)d_in[7];
    const float* conv1_w = (const float*)d_in[8];
    const float* conv1_b = (const float*)d_in[9];
    const float* bn0_g = (const float*)d_in[10];
    const float* bn0_b = (const float*)d_in[11];
    const float* bn1_g = (const float*)d_in[12];
    const float* bn1_b = (const float*)d_in[13];
    const float* mlp0_w = (const float*)d_in[14];
    const float* mlp0_b = (const float*)d_in[15];
    const float* mlp1_w = (const float*)d_in[16];
    const float* mlp1_b = (const float*)d_in[17];
    const float* mlp2_w = (const float*)d_in[18];
    const float* mlp2_b = (const float*)d_in[19];
    const float* bnm0_g = (const float*)d_in[20];
    const float* bnm0_b = (const float*)d_in[21];
    const float* bnm1_g = (const float*)d_in[22];
    const float* bnm1_b = (const float*)d_in[23];
    const float* bnm2_g = (const float*)d_in[24];
    const float* bnm2_b = (const float*)d_in[25];

    float* ws = (float*)d_ws;
    float* dis = ws + OFF_DIS;
    int* rowptr = (int*)(ws + OFF_ROWPTR);
    int* bcursor = (int*)(ws + OFF_CURSOR);
    int* deg = (int*)(ws + OFF_DEG);
    int2* perm = (int2*)(ws + OFF_PERM);
    ushort* xb = (ushort*)(ws + OFF_XB);
    ushort* rdb = (ushort*)(ws + OFF_RDB);
    ushort* B1 = (ushort*)(ws + OFF_B1);
    ushort* B2 = (ushort*)(ws + OFF_B2);
    ushort* B3 = (ushort*)(ws + OFF_B3);
    int2* pbuf = (int2*)(ws + OFF_B1);      // alias: only live before first k_mfma
    ushort* wp = (ushort*)(ws + OFF_WP);
    ushort* WP0 = wp, *WP1 = wp + 10240, *WP2 = wp + 22528, *WP3 = wp + 34816, *WP4 = wp + 38912;
    float* bv = ws + OFF_BV;
    float* st = ws + OFF_STATS;

    hipMemsetAsync(bcursor, 0, (size_t)(2 * NN) * 4, stream);   // bcursor+deg
    hipMemsetAsync(bv, 0, (size_t)(320 + 1920) * 4, stream);    // bvecs+stats

    // CSR build (bucketed two-pass) + static prep
    k_deg<<<(NE + 255) / 256, 256, 0, stream>>>(ecol, deg);
    k_scan<<<1, 1024, 0, stream>>>(deg, rowptr, dis);
    k_scat1<<<(NE + 4095) / 4096, 256, 0, stream>>>(erow, ecol, mask, dis, rowptr, bcursor, pbuf);
    k_scat2<<<NBK, 256, 0, stream>>>(rowptr, pbuf, perm);
    k_prepstats<<<1024, 256, 0, stream>>>(x1, x2, rd, xb, rdb, st);
    k_foldw0<<<1, 256, 0, stream>>>(conv0_w, WP0);

    const int GB = NN / 64;  // 1250 MFMA blocks

    // conv0: lin0 (K=160 padded) -> gather(+bias+elu+stats)
    k_mfma<5, 4, 4, 128, 32, false, false><<<GB, 256, 0, stream>>>(xb, rdb, WP0, bv, B1, nullptr, nullptr);
    k_gather<<<2048, 256, 0, stream>>>(rowptr, perm, B1, conv0_b, B2, st + 256, st + 320);
    k_bnfold192<<<1, 256, 0, stream>>>(st, st + 256, st + 320, bn0_g, bn0_b, conv1_w, nullptr, WP1, bv + 64);

    // conv1: gemm(K=192, BN0-folded) -> gather
    k_mfma<6, 4, 4, 128, 64, false, false><<<GB, 256, 0, stream>>>(xb, B2, WP1, bv + 64, B1, nullptr, nullptr);
    k_gather<<<2048, 256, 0, stream>>>(rowptr, perm, B1, conv1_b, B3, st + 384, st + 448);
    k_bnfold192<<<1, 256, 0, stream>>>(st, st + 384, st + 448, bn1_g, bn1_b, mlp0_w, mlp0_b, WP2, bv + 128);

    // MLP head
    k_mfma<6, 4, 4, 128, 64, true, false><<<GB, 256, 0, stream>>>(xb, B3, WP2, bv + 128, B2, st + 512, st + 576);
    k_bnfold64<<<1, 256, 0, stream>>>(st + 512, st + 576, bnm0_g, bnm0_b, mlp1_w, mlp1_b, WP3, bv + 192, 64);
    k_mfma<2, 4, 2, 64, 64, true, false><<<GB, 256, 0, stream>>>(B2, nullptr, WP3, bv + 192, B1, st + 640, st + 704);
    k_bnfold64<<<1, 256, 0, stream>>>(st + 640, st + 704, bnm1_g, bnm1_b, mlp2_w, mlp2_b, WP4, bv + 256, 32);
    k_mfma<2, 2, 2, 64, 64, true, true><<<GB, 256, 0, stream>>>(B1, nullptr, WP4, bv + 256, B3, st + 768, st + 800);
    k_bnfin<<<1, 32, 0, stream>>>(st + 768, st + 800, bnm2_g, bnm2_b, st + 1856, st + 1888);
    k_out<<<(NN * 32 + 255) / 256, 256, 0, stream>>>((const float*)B3, st + 1856, st + 1888, (float*)d_out);
}

// Round 5
// 739.506 us; speedup vs baseline: 1.2807x; 1.2807x over previous
//
#include <hip/hip_runtime.h>
#include <math.h>

#define NN 80000
#define NE 2560000
#define NBK 313            // ceil(NN/256) buckets of 256 cols
#define BN_EPS 1e-5f

typedef __attribute__((ext_vector_type(8))) short short8;
typedef __attribute__((ext_vector_type(4))) float f32x4;

// ---------------- workspace layout (f32 index units, all 16B-aligned) ----------------
#define OFF_DIS     0                       // NN f32
#define OFF_ROWPTR  80000                   // NN+2 ints
#define OFF_CURSOR  160004                  // NN ints (bcursor[NBK] @0, bsum @1024, boff @2048)
#define OFF_DEG     240004                  // NN ints
#define OFF_PERM    320004                  // 2*NE ints (int2)
#define OFF_XB      (OFF_PERM + 2*NE)       // N*128 bf16 = N*64 f32
#define OFF_RDB     (OFF_XB + NN*64)        // N*32 bf16
#define OFF_B1      (OFF_RDB + NN*16)       // N*64 bf16 (or N*32 f32)
#define OFF_B2      (OFF_B1 + NN*32)
#define OFF_B3      (OFF_B2 + NN*32)
#define OFF_WP      (OFF_B3 + NN*32)        // 40960 ushorts = 20480 f32
#define OFF_BV      (OFF_WP + 20480)        // 5*64 f32
#define OFF_STATS   (OFF_BV + 320)          // 1920 f32
// pbuf (2*NE ints) aliases B1+B2: used only before first k_mfma.

__device__ __forceinline__ ushort f2b(float f) {
    union { float f; unsigned u; } x; x.f = f;
    return (ushort)((x.u + 0x7FFF + ((x.u >> 16) & 1)) >> 16);
}
__device__ __forceinline__ float b2f(ushort u) {
    union { unsigned u; float f; } x; x.u = ((unsigned)u) << 16;
    return x.f;
}

__global__ void k_deg(const int* __restrict__ col, int* __restrict__ deg) {
    int e = blockIdx.x * blockDim.x + threadIdx.x;
    if (e < NE) atomicAdd(&deg[col[e]], 1);
}

// two-level scan, pass A: per-256-chunk reduce -> bsum; also dis = rsqrt(deg)
__global__ void __launch_bounds__(256) k_scanA(const int* __restrict__ deg,
                                               float* __restrict__ dis,
                                               int* __restrict__ bsum) {
    int i = blockIdx.x * 256 + threadIdx.x;
    int d = i < NN ? deg[i] : 0;
    if (i < NN) dis[i] = d > 0 ? rsqrtf((float)d) : 0.f;
    __shared__ int red[256];
    red[threadIdx.x] = d;
    __syncthreads();
    for (int off = 128; off > 0; off >>= 1) {
        if (threadIdx.x < off) red[threadIdx.x] += red[threadIdx.x + off];
        __syncthreads();
    }
    if (threadIdx.x == 0) bsum[blockIdx.x] = red[0];
}

// pass B: single-block scan of the 313 block sums -> boff (exclusive); rowptr[NN]=total
__global__ void __launch_bounds__(512) k_scanB(const int* __restrict__ bsum,
                                               int* __restrict__ boff,
                                               int* __restrict__ rowptr) {
    __shared__ int s[512];
    int t = threadIdx.x;
    int v = t < NBK ? bsum[t] : 0;
    s[t] = v;
    __syncthreads();
    for (int off = 1; off < 512; off <<= 1) {
        int u = t >= off ? s[t - off] : 0;
        __syncthreads();
        s[t] += u;
        __syncthreads();
    }
    if (t < NBK) boff[t] = s[t] - v;
    if (t == NBK - 1) rowptr[NN] = s[t];
}

// pass C: per-chunk exclusive scan + block offset -> rowptr
__global__ void __launch_bounds__(256) k_scanC(const int* __restrict__ deg,
                                               const int* __restrict__ boff,
                                               int* __restrict__ rowptr) {
    int i = blockIdx.x * 256 + threadIdx.x;
    int d = i < NN ? deg[i] : 0;
    __shared__ int s[256];
    s[threadIdx.x] = d;
    __syncthreads();
    for (int off = 1; off < 256; off <<= 1) {
        int u = threadIdx.x >= off ? s[threadIdx.x - off] : 0;
        __syncthreads();
        s[threadIdx.x] += u;
        __syncthreads();
    }
    if (i < NN) rowptr[i] = boff[blockIdx.x] + s[threadIdx.x] - d;
}

// pass 1: bucket-scatter edge records. record = (row<<8 | col&255, coef bits)
__global__ void __launch_bounds__(256) k_scat1(const int* __restrict__ erow,
                                               const int* __restrict__ ecol,
                                               const float* __restrict__ mask,
                                               const float* __restrict__ dis,
                                               const int* __restrict__ rowptr,
                                               int* __restrict__ bcursor,
                                               int2* __restrict__ pbuf) {
    __shared__ int hist[NBK], base[NBK];
    for (int i = threadIdx.x; i < NBK; i += 256) hist[i] = 0;
    __syncthreads();
    int e0 = blockIdx.x * 4096;
    int r[16], c[16], rk[16];
    float cf[16];
    #pragma unroll
    for (int i = 0; i < 16; i++) {
        int e = e0 + i * 256 + threadIdx.x;
        if (e < NE) {
            r[i] = erow[e]; c[i] = ecol[e];
            cf[i] = dis[r[i]] * dis[c[i]] * mask[e];
            rk[i] = atomicAdd(&hist[c[i] >> 8], 1);
        } else c[i] = -1;
    }
    __syncthreads();
    for (int b = threadIdx.x; b < NBK; b += 256) {
        int h = hist[b];
        base[b] = h ? atomicAdd(&bcursor[b], h) : 0;
    }
    __syncthreads();
    #pragma unroll
    for (int i = 0; i < 16; i++) {
        if (c[i] >= 0) {
            int b = c[i] >> 8;
            int addr = rowptr[b << 8] + base[b] + rk[i];
            pbuf[addr] = make_int2((r[i] << 8) | (c[i] & 255), __float_as_int(cf[i]));
        }
    }
}

// pass 2: per-bucket finalize into exact CSR slots
__global__ void __launch_bounds__(256) k_scat2(const int* __restrict__ rowptr,
                                               const int2* __restrict__ pbuf,
                                               int2* __restrict__ perm) {
    __shared__ int rbase[257];
    __shared__ int lcur[256];
    int b = blockIdx.x;
    int c0 = b << 8;
    int ncols = (NN - c0) < 256 ? (NN - c0) : 256;
    int s0 = rowptr[c0];
    if (threadIdx.x < ncols) rbase[threadIdx.x] = rowptr[c0 + threadIdx.x] - s0;
    if (threadIdx.x == 0) rbase[ncols] = rowptr[c0 + ncols] - s0;
    lcur[threadIdx.x] = 0;
    __syncthreads();
    int cnt = rbase[ncols];
    for (int i = threadIdx.x; i < cnt; i += 256) {
        int2 rec = pbuf[s0 + i];
        int crel = rec.x & 255;
        int rr = rec.x >> 8;
        int slot = rbase[crel] + atomicAdd(&lcur[crel], 1);
        perm[s0 + slot] = make_int2(rr, rec.y);
    }
}

// build xb [N,128] bf16, rdb [N,32] bf16 (cols 16-31 zero); fused x1/x2 column stats
__global__ void __launch_bounds__(256) k_prepstats(const float* __restrict__ x1,
                                                   const float* __restrict__ x2,
                                                   const float* __restrict__ rd,
                                                   ushort* __restrict__ xb,
                                                   ushort* __restrict__ rdb,
                                                   float* __restrict__ st) {
    int wave = threadIdx.x >> 6, lane = threadIdx.x & 63;
    float s1 = 0, q1 = 0, s2 = 0, q2 = 0;
    for (int n = blockIdx.x * 4 + wave; n < NN; n += gridDim.x * 4) {
        float a = x1[(size_t)n * 64 + lane];
        float b = x2[(size_t)n * 64 + lane];
        s1 += a; q1 += a * a; s2 += b; q2 += b * b;
        xb[(size_t)n * 128 + lane]      = f2b(a);
        xb[(size_t)n * 128 + 64 + lane] = f2b(b);
        if (lane < 32)
            rdb[(size_t)n * 32 + lane] = lane < 16 ? f2b(rd[(size_t)n * 16 + lane]) : 0;
    }
    __shared__ float red[4][256];
    red[0][threadIdx.x] = s1; red[1][threadIdx.x] = q1;
    red[2][threadIdx.x] = s2; red[3][threadIdx.x] = q2;
    __syncthreads();
    if (threadIdx.x < 64) {
        int l = threadIdx.x;
        atomicAdd(&st[l],       red[0][l] + red[0][l+64] + red[0][l+128] + red[0][l+192]);
        atomicAdd(&st[128 + l], red[1][l] + red[1][l+64] + red[1][l+128] + red[1][l+192]);
        atomicAdd(&st[64 + l],  red[2][l] + red[2][l+64] + red[2][l+128] + red[2][l+192]);
        atomicAdd(&st[192 + l], red[3][l] + red[3][l+64] + red[3][l+128] + red[3][l+192]);
    }
}

// pack lin0 weights (144x64 f32, zero-padded to 160 rows) into MFMA B-frag order
__global__ void k_foldw0(const float* __restrict__ W, ushort* __restrict__ Wp) {
    for (int idx = threadIdx.x; idx < 160 * 64; idx += 256) {
        int k = idx >> 6, c = idx & 63;
        float val = k < 144 ? W[k * 64 + c] : 0.f;
        int ks = k >> 5, j = k & 7, kg = (k >> 3) & 3;
        int l = kg * 16 + (c & 15), ct = c >> 4;
        Wp[((ks * 4 + ct) * 64 + l) * 8 + j] = f2b(val);
    }
}

// BN(192) finalize + fold into packed weights and bias vector
__global__ void k_bnfold192(const float* __restrict__ xs,
                            const float* __restrict__ hsum, const float* __restrict__ hsq,
                            const float* __restrict__ g, const float* __restrict__ bnb,
                            const float* __restrict__ W,     // 192x64 f32
                            const float* __restrict__ bias,  // or null
                            ushort* __restrict__ Wp, float* __restrict__ bvec) {
    __shared__ float scale[192], shift[192];
    int t = threadIdx.x;
    if (t < 192) {
        float s = t < 128 ? xs[t] : hsum[t - 128];
        float q = t < 128 ? xs[128 + t] : hsq[t - 128];
        float m = s * (1.f / NN);
        float var = q * (1.f / NN) - m * m;
        float sc = g[t] * rsqrtf(var + BN_EPS);
        scale[t] = sc;
        shift[t] = bnb[t] - m * sc;
    }
    __syncthreads();
    for (int idx = t; idx < 192 * 64; idx += 256) {
        int k = idx >> 6, c = idx & 63;
        float val = scale[k] * W[idx];
        int ks = k >> 5, j = k & 7, kg = (k >> 3) & 3;
        int l = kg * 16 + (c & 15), ct = c >> 4;
        Wp[((ks * 4 + ct) * 64 + l) * 8 + j] = f2b(val);
    }
    if (t < 64) {
        float acc = bias ? bias[t] : 0.f;
        for (int k = 0; k < 192; k++) acc += shift[k] * W[k * 64 + t];
        bvec[t] = acc;
    }
}

// BN(64) finalize + fold (NCw = 64 or 32 output cols)
__global__ void k_bnfold64(const float* __restrict__ sum, const float* __restrict__ sq,
                           const float* __restrict__ g, const float* __restrict__ bnb,
                           const float* __restrict__ W, const float* __restrict__ bias,
                           ushort* __restrict__ Wp, float* __restrict__ bvec, int NCw) {
    __shared__ float scale[64], shift[64];
    int t = threadIdx.x;
    if (t < 64) {
        float m = sum[t] * (1.f / NN);
        float var = sq[t] * (1.f / NN) - m * m;
        float sc = g[t] * rsqrtf(var + BN_EPS);
        scale[t] = sc;
        shift[t] = bnb[t] - m * sc;
    }
    __syncthreads();
    int NCOLT = NCw >> 4;
    for (int idx = t; idx < 64 * NCw; idx += 256) {
        int k = idx / NCw, c = idx % NCw;
        float val = scale[k] * W[idx];
        int ks = k >> 5, j = k & 7, kg = (k >> 3) & 3;
        int l = kg * 16 + (c & 15), ct = c >> 4;
        Wp[((ks * NCOLT + ct) * 64 + l) * 8 + j] = f2b(val);
    }
    if (t < NCw) {
        float acc = bias[t];
        for (int k = 0; k < 64; k++) acc += shift[k] * W[k * NCw + t];
        bvec[t] = acc;
    }
}

__global__ void k_bnfin(const float* __restrict__ sum, const float* __restrict__ sq,
                        const float* __restrict__ g, const float* __restrict__ b,
                        float* __restrict__ scale, float* __restrict__ shift) {
    int c = threadIdx.x;
    float m = sum[c] * (1.f / NN);
    float var = sq[c] * (1.f / NN) - m * m;
    float sc = g[c] * rsqrtf(var + BN_EPS);
    scale[c] = sc;
    shift[c] = b[c] - m * sc;
}

// ---------------- MFMA GEMM: out[N, NC] = A[N, K] @ Wp + bvec ----------------
template <int KSTEPS, int NCOLT, int KS1, int S1, int S2, bool EPI, bool OUTF32>
__global__ void __launch_bounds__(256) k_mfma(const ushort* __restrict__ A1,
                                              const ushort* __restrict__ A2,
                                              const ushort* __restrict__ Wp,
                                              const float* __restrict__ bvec,
                                              void* __restrict__ out,
                                              float* __restrict__ sum,
                                              float* __restrict__ sq) {
    const int NC = NCOLT * 16;
    __shared__ float cs[NC], cq[NC];
    int wave = threadIdx.x >> 6, lane = threadIdx.x & 63;
    int r0 = lane & 15, kg = lane >> 4;
    int rbase = blockIdx.x * 64 + wave * 16;
    if (EPI) {
        if (threadIdx.x < NC) { cs[threadIdx.x] = 0.f; cq[threadIdx.x] = 0.f; }
        __syncthreads();
    }
    f32x4 acc[NCOLT];
    #pragma unroll
    for (int ct = 0; ct < NCOLT; ct++) acc[ct] = (f32x4){0.f, 0.f, 0.f, 0.f};
    #pragma unroll
    for (int ks = 0; ks < KSTEPS; ks++) {
        const ushort* src = (ks < KS1)
            ? A1 + (size_t)(rbase + r0) * S1 + ks * 32 + kg * 8
            : A2 + (size_t)(rbase + r0) * S2 + (ks - KS1) * 32 + kg * 8;
        short8 a = *reinterpret_cast<const short8*>(src);
        #pragma unroll
        for (int ct = 0; ct < NCOLT; ct++) {
            short8 b = *reinterpret_cast<const short8*>(Wp + ((size_t)(ks * NCOLT + ct) * 64 + lane) * 8);
            acc[ct] = __builtin_amdgcn_mfma_f32_16x16x32_bf16(a, b, acc[ct], 0, 0, 0);
        }
    }
    float ss[NCOLT], qq[NCOLT];
    #pragma unroll
    for (int ct = 0; ct < NCOLT; ct++) {
        int c = ct * 16 + r0;
        float bv = bvec[c];
        ss[ct] = 0.f; qq[ct] = 0.f;
        #pragma unroll
        for (int r = 0; r < 4; r++) {
            int row = rbase + kg * 4 + r;
            float v = acc[ct][r] + bv;
            if (EPI) {
                v = v > 0.f ? v : (__expf(v) - 1.f);
                ss[ct] += v; qq[ct] += v * v;
            }
            if (OUTF32) ((float*)out)[(size_t)row * NC + c] = v;
            else        ((ushort*)out)[(size_t)row * NC + c] = f2b(v);
        }
    }
    if (EPI) {
        #pragma unroll
        for (int ct = 0; ct < NCOLT; ct++) {
            int c = ct * 16 + r0;
            atomicAdd(&cs[c], ss[ct]);
            atomicAdd(&cq[c], qq[ct]);
        }
        __syncthreads();
        if (threadIdx.x < NC) {
            atomicAdd(&sum[threadIdx.x], cs[threadIdx.x]);
            atomicAdd(&sq[threadIdx.x], cq[threadIdx.x]);
        }
    }
}

// CSR gather-aggregate, 8-deep unrolled, dual accumulators
__global__ void __launch_bounds__(256) k_gather(const int* __restrict__ rowptr,
                                                const int2* __restrict__ perm,
                                                const ushort* __restrict__ h,
                                                const float* __restrict__ bias,
                                                ushort* __restrict__ out,
                                                float* __restrict__ sum,
                                                float* __restrict__ sq) {
    int wave = threadIdx.x >> 6, lane = threadIdx.x & 63;
    float bs = bias[lane];
    float s = 0, q = 0;
    for (int n = blockIdx.x * 4 + wave; n < NN; n += gridDim.x * 4) {
        int beg = rowptr[n], end = rowptr[n + 1];
        float acc0 = 0.f, acc1 = 0.f;
        int e = beg;
        for (; e + 8 <= end; e += 8) {
            int2 p0 = perm[e],     p1 = perm[e + 1], p2 = perm[e + 2], p3 = perm[e + 3];
            int2 p4 = perm[e + 4], p5 = perm[e + 5], p6 = perm[e + 6], p7 = perm[e + 7];
            float v0 = b2f(h[(size_t)p0.x * 64 + lane]);
            float v1 = b2f(h[(size_t)p1.x * 64 + lane]);
            float v2 = b2f(h[(size_t)p2.x * 64 + lane]);
            float v3 = b2f(h[(size_t)p3.x * 64 + lane]);
            float v4 = b2f(h[(size_t)p4.x * 64 + lane]);
            float v5 = b2f(h[(size_t)p5.x * 64 + lane]);
            float v6 = b2f(h[(size_t)p6.x * 64 + lane]);
            float v7 = b2f(h[(size_t)p7.x * 64 + lane]);
            acc0 += __int_as_float(p0.y) * v0; acc1 += __int_as_float(p1.y) * v1;
            acc0 += __int_as_float(p2.y) * v2; acc1 += __int_as_float(p3.y) * v3;
            acc0 += __int_as_float(p4.y) * v4; acc1 += __int_as_float(p5.y) * v5;
            acc0 += __int_as_float(p6.y) * v6; acc1 += __int_as_float(p7.y) * v7;
        }
        for (; e < end; e++) {
            int2 p = perm[e];
            acc0 += __int_as_float(p.y) * b2f(h[(size_t)p.x * 64 + lane]);
        }
        float v = acc0 + acc1 + bs;
        v = v > 0.f ? v : (__expf(v) - 1.f);
        out[(size_t)n * 64 + lane] = f2b(v);
        s += v; q += v * v;
    }
    __shared__ float rs[256], rq[256];
    rs[threadIdx.x] = s; rq[threadIdx.x] = q;
    __syncthreads();
    if (threadIdx.x < 64) {
        int l = threadIdx.x;
        atomicAdd(&sum[l], rs[l] + rs[l + 64] + rs[l + 128] + rs[l + 192]);
        atomicAdd(&sq[l],  rq[l] + rq[l + 64] + rq[l + 128] + rq[l + 192]);
    }
}

__global__ void k_out(const float* __restrict__ u2, const float* __restrict__ scale,
                      const float* __restrict__ shift, float* __restrict__ out) {
    int t = blockIdx.x * blockDim.x + threadIdx.x;
    if (t < NN * 32) {
        int c = t & 31;
        out[t] = u2[t] * scale[c] + shift[c];
    }
}

extern "C" void kernel_launch(void* const* d_in, const int* in_sizes, int n_in,
                              void* d_out, int out_size, void* d_ws, size_t ws_size,
                              hipStream_t stream) {
    const float* x1 = (const float*)d_in[0];
    const float* x2 = (const float*)d_in[1];
    const float* rd = (const float*)d_in[2];
    const float* mask = (const float*)d_in[4];
    const int* ei = (const int*)d_in[5];
    const int* erow = ei;
    const int* ecol = ei + NE;
    const float* conv0_w = (const float*)d_in[6];
    const float* conv0_b = (const float*)d_in[7];
    const float* conv1_w = (const float*)d_in[8];
    const float* conv1_b = (const float*)d_in[9];
    const float* bn0_g = (const float*)d_in[10];
    const float* bn0_b = (const float*)d_in[11];
    const float* bn1_g = (const float*)d_in[12];
    const float* bn1_b = (const float*)d_in[13];
    const float* mlp0_w = (const float*)d_in[14];
    const float* mlp0_b = (const float*)d_in[15];
    const float* mlp1_w = (const float*)d_in[16];
    const float* mlp1_b = (const float*)d_in[17];
    const float* mlp2_w = (const float*)d_in[18];
    const float* mlp2_b = (const float*)d_in[19];
    const float* bnm0_g = (const float*)d_in[20];
    const float* bnm0_b = (const float*)d_in[21];
    const float* bnm1_g = (const float*)d_in[22];
    const float* bnm1_b = (const float*)d_in[23];
    const float* bnm2_g = (const float*)d_in[24];
    const float* bnm2_b = (const float*)d_in[25];

    float* ws = (float*)d_ws;
    float* dis = ws + OFF_DIS;
    int* rowptr = (int*)(ws + OFF_ROWPTR);
    int* bcursor = (int*)(ws + OFF_CURSOR);
    int* bsum = bcursor + 1024;
    int* boff = bcursor + 2048;
    int* deg = (int*)(ws + OFF_DEG);
    int2* perm = (int2*)(ws + OFF_PERM);
    ushort* xb = (ushort*)(ws + OFF_XB);
    ushort* rdb = (ushort*)(ws + OFF_RDB);
    ushort* B1 = (ushort*)(ws + OFF_B1);
    ushort* B2 = (ushort*)(ws + OFF_B2);
    ushort* B3 = (ushort*)(ws + OFF_B3);
    int2* pbuf = (int2*)(ws + OFF_B1);      // alias: only live before first k_mfma
    ushort* wp = (ushort*)(ws + OFF_WP);
    ushort* WP0 = wp, *WP1 = wp + 10240, *WP2 = wp + 22528, *WP3 = wp + 34816, *WP4 = wp + 38912;
    float* bv = ws + OFF_BV;
    float* st = ws + OFF_STATS;

    hipMemsetAsync(bcursor, 0, (size_t)(2 * NN) * 4, stream);   // bcursor+scanbufs+deg
    hipMemsetAsync(bv, 0, (size_t)(320 + 1920) * 4, stream);    // bvecs+stats

    // CSR build: histogram -> two-level scan -> bucketed two-pass permute
    k_deg<<<(NE + 255) / 256, 256, 0, stream>>>(ecol, deg);
    k_scanA<<<NBK, 256, 0, stream>>>(deg, dis, bsum);
    k_scanB<<<1, 512, 0, stream>>>(bsum, boff, rowptr);
    k_scanC<<<NBK, 256, 0, stream>>>(deg, boff, rowptr);
    k_scat1<<<(NE + 4095) / 4096, 256, 0, stream>>>(erow, ecol, mask, dis, rowptr, bcursor, pbuf);
    k_scat2<<<NBK, 256, 0, stream>>>(rowptr, pbuf, perm);
    k_prepstats<<<1024, 256, 0, stream>>>(x1, x2, rd, xb, rdb, st);
    k_foldw0<<<1, 256, 0, stream>>>(conv0_w, WP0);

    const int GB = NN / 64;  // 1250 MFMA blocks

    // conv0: lin0 (K=160 padded) -> gather(+bias+elu+stats)
    k_mfma<5, 4, 4, 128, 32, false, false><<<GB, 256, 0, stream>>>(xb, rdb, WP0, bv, B1, nullptr, nullptr);
    k_gather<<<2048, 256, 0, stream>>>(rowptr, perm, B1, conv0_b, B2, st + 256, st + 320);
    k_bnfold192<<<1, 256, 0, stream>>>(st, st + 256, st + 320, bn0_g, bn0_b, conv1_w, nullptr, WP1, bv + 64);

    // conv1: gemm(K=192, BN0-folded) -> gather
    k_mfma<6, 4, 4, 128, 64, false, false><<<GB, 256, 0, stream>>>(xb, B2, WP1, bv + 64, B1, nullptr, nullptr);
    k_gather<<<2048, 256, 0, stream>>>(rowptr, perm, B1, conv1_b, B3, st + 384, st + 448);
    k_bnfold192<<<1, 256, 0, stream>>>(st, st + 384, st + 448, bn1_g, bn1_b, mlp0_w, mlp0_b, WP2, bv + 128);

    // MLP head
    k_mfma<6, 4, 4, 128, 64, true, false><<<GB, 256, 0, stream>>>(xb, B3, WP2, bv + 128, B2, st + 512, st + 576);
    k_bnfold64<<<1, 256, 0, stream>>>(st + 512, st + 576, bnm0_g, bnm0_b, mlp1_w, mlp1_b, WP3, bv + 192, 64);
    k_mfma<2, 4, 2, 64, 64, true, false><<<GB, 256, 0, stream>>>(B2, nullptr, WP3, bv + 192, B1, st + 640, st + 704);
    k_bnfold64<<<1, 256, 0, stream>>>(st + 640, st + 704, bnm1_g, bnm1_b, mlp2_w, mlp2_b, WP4, bv + 256, 32);
    k_mfma<2, 2, 2, 64, 64, true, true><<<GB, 256, 0, stream>>>(B1, nullptr, WP4, bv + 256, B3, st + 768, st + 800);
    k_bnfin<<<1, 32, 0, stream>>>(st + 768, st + 800, bnm2_g, bnm2_b, st + 1856, st + 1888);
    k_out<<<(NN * 32 + 255) / 256, 256, 0, stream>>>((const float*)B3, st + 1856, st + 1888, (float*)d_out);
}

// Round 6
// 704.479 us; speedup vs baseline: 1.3444x; 1.0497x over previous
//
#include <hip/hip_runtime.h>
#include <math.h>

#define NN 80000
#define NE 2560000
#define NBK 313            // ceil(NN/256) buckets of 256 cols
#define BN_EPS 1e-5f

typedef __attribute__((ext_vector_type(8))) short short8;
typedef __attribute__((ext_vector_type(8))) unsigned short ushort8;
typedef __attribute__((ext_vector_type(4))) float f32x4;

// ---------------- workspace layout (f32 index units, all 16B-aligned) ----------------
#define OFF_DIS     0                       // NN f32
#define OFF_ROWPTR  80000                   // NN+2 ints
#define OFF_CURSOR  160004                  // NN ints (bcursor[NBK] @0, bsum @1024, boff @2048)
#define OFF_DEG     240004                  // NN ints
#define OFF_PERM    320004                  // 2*NE ints (int2)
#define OFF_XB      (OFF_PERM + 2*NE)       // N*128 bf16 = N*64 f32
#define OFF_RDB     (OFF_XB + NN*64)        // N*32 bf16
#define OFF_B1      (OFF_RDB + NN*16)       // N*64 bf16 (or N*32 f32)
#define OFF_B2      (OFF_B1 + NN*32)
#define OFF_B3      (OFF_B2 + NN*32)
#define OFF_WP      (OFF_B3 + NN*32)        // 40960 ushorts = 20480 f32
#define OFF_BV      (OFF_WP + 20480)        // 5*64 f32
#define OFF_STATS   (OFF_BV + 320)          // 1920 f32
// pbuf (2*NE ints) aliases B1+B2: used only before first k_mfma.

__device__ __forceinline__ ushort f2b(float f) {
    union { float f; unsigned u; } x; x.f = f;
    return (ushort)((x.u + 0x7FFF + ((x.u >> 16) & 1)) >> 16);
}
__device__ __forceinline__ float b2f(ushort u) {
    union { unsigned u; float f; } x; x.u = ((unsigned)u) << 16;
    return x.f;
}

__global__ void k_deg(const int* __restrict__ col, int* __restrict__ deg) {
    int e = blockIdx.x * blockDim.x + threadIdx.x;
    if (e < NE) atomicAdd(&deg[col[e]], 1);
}

// two-level scan, pass A: per-256-chunk reduce -> bsum; also dis = rsqrt(deg)
__global__ void __launch_bounds__(256) k_scanA(const int* __restrict__ deg,
                                               float* __restrict__ dis,
                                               int* __restrict__ bsum) {
    int i = blockIdx.x * 256 + threadIdx.x;
    int d = i < NN ? deg[i] : 0;
    if (i < NN) dis[i] = d > 0 ? rsqrtf((float)d) : 0.f;
    __shared__ int red[256];
    red[threadIdx.x] = d;
    __syncthreads();
    for (int off = 128; off > 0; off >>= 1) {
        if (threadIdx.x < off) red[threadIdx.x] += red[threadIdx.x + off];
        __syncthreads();
    }
    if (threadIdx.x == 0) bsum[blockIdx.x] = red[0];
}

// pass B: single-block scan of the 313 block sums -> boff (exclusive); rowptr[NN]=total
__global__ void __launch_bounds__(512) k_scanB(const int* __restrict__ bsum,
                                               int* __restrict__ boff,
                                               int* __restrict__ rowptr) {
    __shared__ int s[512];
    int t = threadIdx.x;
    int v = t < NBK ? bsum[t] : 0;
    s[t] = v;
    __syncthreads();
    for (int off = 1; off < 512; off <<= 1) {
        int u = t >= off ? s[t - off] : 0;
        __syncthreads();
        s[t] += u;
        __syncthreads();
    }
    if (t < NBK) boff[t] = s[t] - v;
    if (t == NBK - 1) rowptr[NN] = s[t];
}

// pass C: per-chunk exclusive scan + block offset -> rowptr
__global__ void __launch_bounds__(256) k_scanC(const int* __restrict__ deg,
                                               const int* __restrict__ boff,
                                               int* __restrict__ rowptr) {
    int i = blockIdx.x * 256 + threadIdx.x;
    int d = i < NN ? deg[i] : 0;
    __shared__ int s[256];
    s[threadIdx.x] = d;
    __syncthreads();
    for (int off = 1; off < 256; off <<= 1) {
        int u = threadIdx.x >= off ? s[threadIdx.x - off] : 0;
        __syncthreads();
        s[threadIdx.x] += u;
        __syncthreads();
    }
    if (i < NN) rowptr[i] = boff[blockIdx.x] + s[threadIdx.x] - d;
}

// pass 1: bucket-scatter edge records. record = (row<<8 | col&255, coef bits)
__global__ void __launch_bounds__(256) k_scat1(const int* __restrict__ erow,
                                               const int* __restrict__ ecol,
                                               const float* __restrict__ mask,
                                               const float* __restrict__ dis,
                                               const int* __restrict__ rowptr,
                                               int* __restrict__ bcursor,
                                               int2* __restrict__ pbuf) {
    __shared__ int hist[NBK], base[NBK];
    for (int i = threadIdx.x; i < NBK; i += 256) hist[i] = 0;
    __syncthreads();
    int e0 = blockIdx.x * 4096;
    int r[16], c[16], rk[16];
    float cf[16];
    #pragma unroll
    for (int i = 0; i < 16; i++) {
        int e = e0 + i * 256 + threadIdx.x;
        if (e < NE) {
            r[i] = erow[e]; c[i] = ecol[e];
            cf[i] = dis[r[i]] * dis[c[i]] * mask[e];
            rk[i] = atomicAdd(&hist[c[i] >> 8], 1);
        } else c[i] = -1;
    }
    __syncthreads();
    for (int b = threadIdx.x; b < NBK; b += 256) {
        int h = hist[b];
        base[b] = h ? atomicAdd(&bcursor[b], h) : 0;
    }
    __syncthreads();
    #pragma unroll
    for (int i = 0; i < 16; i++) {
        if (c[i] >= 0) {
            int b = c[i] >> 8;
            int addr = rowptr[b << 8] + base[b] + rk[i];
            pbuf[addr] = make_int2((r[i] << 8) | (c[i] & 255), __float_as_int(cf[i]));
        }
    }
}

// pass 2: per-bucket finalize into exact CSR slots
__global__ void __launch_bounds__(256) k_scat2(const int* __restrict__ rowptr,
                                               const int2* __restrict__ pbuf,
                                               int2* __restrict__ perm) {
    __shared__ int rbase[257];
    __shared__ int lcur[256];
    int b = blockIdx.x;
    int c0 = b << 8;
    int ncols = (NN - c0) < 256 ? (NN - c0) : 256;
    int s0 = rowptr[c0];
    if (threadIdx.x < ncols) rbase[threadIdx.x] = rowptr[c0 + threadIdx.x] - s0;
    if (threadIdx.x == 0) rbase[ncols] = rowptr[c0 + ncols] - s0;
    lcur[threadIdx.x] = 0;
    __syncthreads();
    int cnt = rbase[ncols];
    for (int i = threadIdx.x; i < cnt; i += 256) {
        int2 rec = pbuf[s0 + i];
        int crel = rec.x & 255;
        int rr = rec.x >> 8;
        int slot = rbase[crel] + atomicAdd(&lcur[crel], 1);
        perm[s0 + slot] = make_int2(rr, rec.y);
    }
}

// build xb [N,128] bf16, rdb [N,32] bf16 (cols 16-31 zero); fused x1/x2 column stats
__global__ void __launch_bounds__(256) k_prepstats(const float* __restrict__ x1,
                                                   const float* __restrict__ x2,
                                                   const float* __restrict__ rd,
                                                   ushort* __restrict__ xb,
                                                   ushort* __restrict__ rdb,
                                                   float* __restrict__ st) {
    int wave = threadIdx.x >> 6, lane = threadIdx.x & 63;
    float s1 = 0, q1 = 0, s2 = 0, q2 = 0;
    for (int n = blockIdx.x * 4 + wave; n < NN; n += gridDim.x * 4) {
        float a = x1[(size_t)n * 64 + lane];
        float b = x2[(size_t)n * 64 + lane];
        s1 += a; q1 += a * a; s2 += b; q2 += b * b;
        xb[(size_t)n * 128 + lane]      = f2b(a);
        xb[(size_t)n * 128 + 64 + lane] = f2b(b);
        if (lane < 32)
            rdb[(size_t)n * 32 + lane] = lane < 16 ? f2b(rd[(size_t)n * 16 + lane]) : 0;
    }
    __shared__ float red[4][256];
    red[0][threadIdx.x] = s1; red[1][threadIdx.x] = q1;
    red[2][threadIdx.x] = s2; red[3][threadIdx.x] = q2;
    __syncthreads();
    if (threadIdx.x < 64) {
        int l = threadIdx.x;
        atomicAdd(&st[l],       red[0][l] + red[0][l+64] + red[0][l+128] + red[0][l+192]);
        atomicAdd(&st[128 + l], red[1][l] + red[1][l+64] + red[1][l+128] + red[1][l+192]);
        atomicAdd(&st[64 + l],  red[2][l] + red[2][l+64] + red[2][l+128] + red[2][l+192]);
        atomicAdd(&st[192 + l], red[3][l] + red[3][l+64] + red[3][l+128] + red[3][l+192]);
    }
}

// pack lin0 weights (144x64 f32, zero-padded to 160 rows) into MFMA B-frag order
__global__ void k_foldw0(const float* __restrict__ W, ushort* __restrict__ Wp) {
    for (int idx = threadIdx.x; idx < 160 * 64; idx += 256) {
        int k = idx >> 6, c = idx & 63;
        float val = k < 144 ? W[k * 64 + c] : 0.f;
        int ks = k >> 5, j = k & 7, kg = (k >> 3) & 3;
        int l = kg * 16 + (c & 15), ct = c >> 4;
        Wp[((ks * 4 + ct) * 64 + l) * 8 + j] = f2b(val);
    }
}

// BN(192) finalize + fold into packed weights and bias vector
__global__ void k_bnfold192(const float* __restrict__ xs,
                            const float* __restrict__ hsum, const float* __restrict__ hsq,
                            const float* __restrict__ g, const float* __restrict__ bnb,
                            const float* __restrict__ W,     // 192x64 f32
                            const float* __restrict__ bias,  // or null
                            ushort* __restrict__ Wp, float* __restrict__ bvec) {
    __shared__ float scale[192], shift[192];
    int t = threadIdx.x;
    if (t < 192) {
        float s = t < 128 ? xs[t] : hsum[t - 128];
        float q = t < 128 ? xs[128 + t] : hsq[t - 128];
        float m = s * (1.f / NN);
        float var = q * (1.f / NN) - m * m;
        float sc = g[t] * rsqrtf(var + BN_EPS);
        scale[t] = sc;
        shift[t] = bnb[t] - m * sc;
    }
    __syncthreads();
    for (int idx = t; idx < 192 * 64; idx += 256) {
        int k = idx >> 6, c = idx & 63;
        float val = scale[k] * W[idx];
        int ks = k >> 5, j = k & 7, kg = (k >> 3) & 3;
        int l = kg * 16 + (c & 15), ct = c >> 4;
        Wp[((ks * 4 + ct) * 64 + l) * 8 + j] = f2b(val);
    }
    if (t < 64) {
        float acc = bias ? bias[t] : 0.f;
        for (int k = 0; k < 192; k++) acc += shift[k] * W[k * 64 + t];
        bvec[t] = acc;
    }
}

// BN(64) finalize + fold (NCw = 64 or 32 output cols)
__global__ void k_bnfold64(const float* __restrict__ sum, const float* __restrict__ sq,
                           const float* __restrict__ g, const float* __restrict__ bnb,
                           const float* __restrict__ W, const float* __restrict__ bias,
                           ushort* __restrict__ Wp, float* __restrict__ bvec, int NCw) {
    __shared__ float scale[64], shift[64];
    int t = threadIdx.x;
    if (t < 64) {
        float m = sum[t] * (1.f / NN);
        float var = sq[t] * (1.f / NN) - m * m;
        float sc = g[t] * rsqrtf(var + BN_EPS);
        scale[t] = sc;
        shift[t] = bnb[t] - m * sc;
    }
    __syncthreads();
    int NCOLT = NCw >> 4;
    for (int idx = t; idx < 64 * NCw; idx += 256) {
        int k = idx / NCw, c = idx % NCw;
        float val = scale[k] * W[idx];
        int ks = k >> 5, j = k & 7, kg = (k >> 3) & 3;
        int l = kg * 16 + (c & 15), ct = c >> 4;
        Wp[((ks * NCOLT + ct) * 64 + l) * 8 + j] = f2b(val);
    }
    if (t < NCw) {
        float acc = bias[t];
        for (int k = 0; k < 64; k++) acc += shift[k] * W[k * NCw + t];
        bvec[t] = acc;
    }
}

__global__ void k_bnfin(const float* __restrict__ sum, const float* __restrict__ sq,
                        const float* __restrict__ g, const float* __restrict__ b,
                        float* __restrict__ scale, float* __restrict__ shift) {
    int c = threadIdx.x;
    float m = sum[c] * (1.f / NN);
    float var = sq[c] * (1.f / NN) - m * m;
    float sc = g[c] * rsqrtf(var + BN_EPS);
    scale[c] = sc;
    shift[c] = b[c] - m * sc;
}

// ---------------- MFMA GEMM: out[N, NC] = A[N, K] @ Wp + bvec ----------------
template <int KSTEPS, int NCOLT, int KS1, int S1, int S2, bool EPI, bool OUTF32>
__global__ void __launch_bounds__(256) k_mfma(const ushort* __restrict__ A1,
                                              const ushort* __restrict__ A2,
                                              const ushort* __restrict__ Wp,
                                              const float* __restrict__ bvec,
                                              void* __restrict__ out,
                                              float* __restrict__ sum,
                                              float* __restrict__ sq) {
    const int NC = NCOLT * 16;
    __shared__ float cs[NC], cq[NC];
    int wave = threadIdx.x >> 6, lane = threadIdx.x & 63;
    int r0 = lane & 15, kg = lane >> 4;
    int rbase = blockIdx.x * 64 + wave * 16;
    if (EPI) {
        if (threadIdx.x < NC) { cs[threadIdx.x] = 0.f; cq[threadIdx.x] = 0.f; }
        __syncthreads();
    }
    f32x4 acc[NCOLT];
    #pragma unroll
    for (int ct = 0; ct < NCOLT; ct++) acc[ct] = (f32x4){0.f, 0.f, 0.f, 0.f};
    #pragma unroll
    for (int ks = 0; ks < KSTEPS; ks++) {
        const ushort* src = (ks < KS1)
            ? A1 + (size_t)(rbase + r0) * S1 + ks * 32 + kg * 8
            : A2 + (size_t)(rbase + r0) * S2 + (ks - KS1) * 32 + kg * 8;
        short8 a = *reinterpret_cast<const short8*>(src);
        #pragma unroll
        for (int ct = 0; ct < NCOLT; ct++) {
            short8 b = *reinterpret_cast<const short8*>(Wp + ((size_t)(ks * NCOLT + ct) * 64 + lane) * 8);
            acc[ct] = __builtin_amdgcn_mfma_f32_16x16x32_bf16(a, b, acc[ct], 0, 0, 0);
        }
    }
    float ss[NCOLT], qq[NCOLT];
    #pragma unroll
    for (int ct = 0; ct < NCOLT; ct++) {
        int c = ct * 16 + r0;
        float bv = bvec[c];
        ss[ct] = 0.f; qq[ct] = 0.f;
        #pragma unroll
        for (int r = 0; r < 4; r++) {
            int row = rbase + kg * 4 + r;
            float v = acc[ct][r] + bv;
            if (EPI) {
                v = v > 0.f ? v : (__expf(v) - 1.f);
                ss[ct] += v; qq[ct] += v * v;
            }
            if (OUTF32) ((float*)out)[(size_t)row * NC + c] = v;
            else        ((ushort*)out)[(size_t)row * NC + c] = f2b(v);
        }
    }
    if (EPI) {
        #pragma unroll
        for (int ct = 0; ct < NCOLT; ct++) {
            int c = ct * 16 + r0;
            atomicAdd(&cs[c], ss[ct]);
            atomicAdd(&cq[c], qq[ct]);
        }
        __syncthreads();
        if (threadIdx.x < NC) {
            atomicAdd(&sum[threadIdx.x], cs[threadIdx.x]);
            atomicAdd(&sq[threadIdx.x], cq[threadIdx.x]);
        }
    }
}

// CSR gather-aggregate: 8 lanes per edge (ushort8 = 16B/lane), 8 edges per wave-step,
// 4-step unroll -> 32 row-gathers in flight per wave. Cross-group shfl reduce at node end.
__global__ void __launch_bounds__(256) k_gather(const int* __restrict__ rowptr,
                                                const int2* __restrict__ perm,
                                                const ushort* __restrict__ h,
                                                const float* __restrict__ bias,
                                                ushort* __restrict__ out,
                                                float* __restrict__ sum,
                                                float* __restrict__ sq) {
    __shared__ float cs[64], cq[64];
    if (threadIdx.x < 64) { cs[threadIdx.x] = 0.f; cq[threadIdx.x] = 0.f; }
    __syncthreads();
    int wave = threadIdx.x >> 6, lane = threadIdx.x & 63;
    int g = lane >> 3, c8 = lane & 7;        // edge-slot group, column-octet
    const ushort* hb = h + c8 * 8;
    float bs[8];
    #pragma unroll
    for (int j = 0; j < 8; j++) bs[j] = bias[c8 * 8 + j];
    float sArr[8], qArr[8];
    #pragma unroll
    for (int j = 0; j < 8; j++) { sArr[j] = 0.f; qArr[j] = 0.f; }

    for (int n = blockIdx.x * 4 + wave; n < NN; n += gridDim.x * 4) {
        int beg = rowptr[n], end = rowptr[n + 1];
        float acc[8];
        #pragma unroll
        for (int j = 0; j < 8; j++) acc[j] = 0.f;
        int e = beg;
        for (; e + 32 <= end; e += 32) {
            int2 p0 = perm[e + g];
            int2 p1 = perm[e + 8 + g];
            int2 p2 = perm[e + 16 + g];
            int2 p3 = perm[e + 24 + g];
            ushort8 h0 = *reinterpret_cast<const ushort8*>(hb + (size_t)p0.x * 64);
            ushort8 h1 = *reinterpret_cast<const ushort8*>(hb + (size_t)p1.x * 64);
            ushort8 h2 = *reinterpret_cast<const ushort8*>(hb + (size_t)p2.x * 64);
            ushort8 h3 = *reinterpret_cast<const ushort8*>(hb + (size_t)p3.x * 64);
            float c0 = __int_as_float(p0.y), c1 = __int_as_float(p1.y);
            float c2 = __int_as_float(p2.y), c3 = __int_as_float(p3.y);
            #pragma unroll
            for (int j = 0; j < 8; j++) {
                acc[j] += c0 * b2f(h0[j]);
                acc[j] += c1 * b2f(h1[j]);
                acc[j] += c2 * b2f(h2[j]);
                acc[j] += c3 * b2f(h3[j]);
            }
        }
        for (; e < end; e += 8) {
            int ee = e + g;
            int2 p = make_int2(0, 0);
            if (ee < end) p = perm[ee];
            ushort8 hv = *reinterpret_cast<const ushort8*>(hb + (size_t)p.x * 64);
            float cf = __int_as_float(p.y);
            #pragma unroll
            for (int j = 0; j < 8; j++) acc[j] += cf * b2f(hv[j]);
        }
        // combine the 8 edge-groups
        #pragma unroll
        for (int j = 0; j < 8; j++) {
            float a = acc[j];
            a += __shfl_xor(a, 8, 64);
            a += __shfl_xor(a, 16, 64);
            a += __shfl_xor(a, 32, 64);
            acc[j] = a;
        }
        if (g == 0) {
            ushort8 ov;
            #pragma unroll
            for (int j = 0; j < 8; j++) {
                float v = acc[j] + bs[j];
                v = v > 0.f ? v : (__expf(v) - 1.f);
                sArr[j] += v; qArr[j] += v * v;
                ov[j] = f2b(v);
            }
            *reinterpret_cast<ushort8*>(out + (size_t)n * 64 + c8 * 8) = ov;
        }
    }
    if (g == 0) {
        #pragma unroll
        for (int j = 0; j < 8; j++) {
            atomicAdd(&cs[c8 * 8 + j], sArr[j]);
            atomicAdd(&cq[c8 * 8 + j], qArr[j]);
        }
    }
    __syncthreads();
    if (threadIdx.x < 64) {
        atomicAdd(&sum[threadIdx.x], cs[threadIdx.x]);
        atomicAdd(&sq[threadIdx.x], cq[threadIdx.x]);
    }
}

__global__ void k_out(const float* __restrict__ u2, const float* __restrict__ scale,
                      const float* __restrict__ shift, float* __restrict__ out) {
    int t = blockIdx.x * blockDim.x + threadIdx.x;
    if (t < NN * 32) {
        int c = t & 31;
        out[t] = u2[t] * scale[c] + shift[c];
    }
}

extern "C" void kernel_launch(void* const* d_in, const int* in_sizes, int n_in,
                              void* d_out, int out_size, void* d_ws, size_t ws_size,
                              hipStream_t stream) {
    const float* x1 = (const float*)d_in[0];
    const float* x2 = (const float*)d_in[1];
    const float* rd = (const float*)d_in[2];
    const float* mask = (const float*)d_in[4];
    const int* ei = (const int*)d_in[5];
    const int* erow = ei;
    const int* ecol = ei + NE;
    const float* conv0_w = (const float*)d_in[6];
    const float* conv0_b = (const float*)d_in[7];
    const float* conv1_w = (const float*)d_in[8];
    const float* conv1_b = (const float*)d_in[9];
    const float* bn0_g = (const float*)d_in[10];
    const float* bn0_b = (const float*)d_in[11];
    const float* bn1_g = (const float*)d_in[12];
    const float* bn1_b = (const float*)d_in[13];
    const float* mlp0_w = (const float*)d_in[14];
    const float* mlp0_b = (const float*)d_in[15];
    const float* mlp1_w = (const float*)d_in[16];
    const float* mlp1_b = (const float*)d_in[17];
    const float* mlp2_w = (const float*)d_in[18];
    const float* mlp2_b = (const float*)d_in[19];
    const float* bnm0_g = (const float*)d_in[20];
    const float* bnm0_b = (const float*)d_in[21];
    const float* bnm1_g = (const float*)d_in[22];
    const float* bnm1_b = (const float*)d_in[23];
    const float* bnm2_g = (const float*)d_in[24];
    const float* bnm2_b = (const float*)d_in[25];

    float* ws = (float*)d_ws;
    float* dis = ws + OFF_DIS;
    int* rowptr = (int*)(ws + OFF_ROWPTR);
    int* bcursor = (int*)(ws + OFF_CURSOR);
    int* bsum = bcursor + 1024;
    int* boff = bcursor + 2048;
    int* deg = (int*)(ws + OFF_DEG);
    int2* perm = (int2*)(ws + OFF_PERM);
    ushort* xb = (ushort*)(ws + OFF_XB);
    ushort* rdb = (ushort*)(ws + OFF_RDB);
    ushort* B1 = (ushort*)(ws + OFF_B1);
    ushort* B2 = (ushort*)(ws + OFF_B2);
    ushort* B3 = (ushort*)(ws + OFF_B3);
    int2* pbuf = (int2*)(ws + OFF_B1);      // alias: only live before first k_mfma
    ushort* wp = (ushort*)(ws + OFF_WP);
    ushort* WP0 = wp, *WP1 = wp + 10240, *WP2 = wp + 22528, *WP3 = wp + 34816, *WP4 = wp + 38912;
    float* bv = ws + OFF_BV;
    float* st = ws + OFF_STATS;

    hipMemsetAsync(bcursor, 0, (size_t)(2 * NN) * 4, stream);   // bcursor+scanbufs+deg
    hipMemsetAsync(bv, 0, (size_t)(320 + 1920) * 4, stream);    // bvecs+stats

    // CSR build: histogram -> two-level scan -> bucketed two-pass permute
    k_deg<<<(NE + 255) / 256, 256, 0, stream>>>(ecol, deg);
    k_scanA<<<NBK, 256, 0, stream>>>(deg, dis, bsum);
    k_scanB<<<1, 512, 0, stream>>>(bsum, boff, rowptr);
    k_scanC<<<NBK, 256, 0, stream>>>(deg, boff, rowptr);
    k_scat1<<<(NE + 4095) / 4096, 256, 0, stream>>>(erow, ecol, mask, dis, rowptr, bcursor, pbuf);
    k_scat2<<<NBK, 256, 0, stream>>>(rowptr, pbuf, perm);
    k_prepstats<<<1024, 256, 0, stream>>>(x1, x2, rd, xb, rdb, st);
    k_foldw0<<<1, 256, 0, stream>>>(conv0_w, WP0);

    const int GB = NN / 64;  // 1250 MFMA blocks

    // conv0: lin0 (K=160 padded) -> gather(+bias+elu+stats)
    k_mfma<5, 4, 4, 128, 32, false, false><<<GB, 256, 0, stream>>>(xb, rdb, WP0, bv, B1, nullptr, nullptr);
    k_gather<<<2048, 256, 0, stream>>>(rowptr, perm, B1, conv0_b, B2, st + 256, st + 320);
    k_bnfold192<<<1, 256, 0, stream>>>(st, st + 256, st + 320, bn0_g, bn0_b, conv1_w, nullptr, WP1, bv + 64);

    // conv1: gemm(K=192, BN0-folded) -> gather
    k_mfma<6, 4, 4, 128, 64, false, false><<<GB, 256, 0, stream>>>(xb, B2, WP1, bv + 64, B1, nullptr, nullptr);
    k_gather<<<2048, 256, 0, stream>>>(rowptr, perm, B1, conv1_b, B3, st + 384, st + 448);
    k_bnfold192<<<1, 256, 0, stream>>>(st, st + 384, st + 448, bn1_g, bn1_b, mlp0_w, mlp0_b, WP2, bv + 128);

    // MLP head
    k_mfma<6, 4, 4, 128, 64, true, false><<<GB, 256, 0, stream>>>(xb, B3, WP2, bv + 128, B2, st + 512, st + 576);
    k_bnfold64<<<1, 256, 0, stream>>>(st + 512, st + 576, bnm0_g, bnm0_b, mlp1_w, mlp1_b, WP3, bv + 192, 64);
    k_mfma<2, 4, 2, 64, 64, true, false><<<GB, 256, 0, stream>>>(B2, nullptr, WP3, bv + 192, B1, st + 640, st + 704);
    k_bnfold64<<<1, 256, 0, stream>>>(st + 640, st + 704, bnm1_g, bnm1_b, mlp2_w, mlp2_b, WP4, bv + 256, 32);
    k_mfma<2, 2, 2, 64, 64, true, true><<<GB, 256, 0, stream>>>(B1, nullptr, WP4, bv + 256, B3, st + 768, st + 800);
    k_bnfin<<<1, 32, 0, stream>>>(st + 768, st + 800, bnm2_g, bnm2_b, st + 1856, st + 1888);
    k_out<<<(NN * 32 + 255) / 256, 256, 0, stream>>>((const float*)B3, st + 1856, st + 1888, (float*)d_out);
}